// Round 5
// baseline (253.776 us; speedup 1.0000x reference)
//
#include <hip/hip_runtime.h>
#include <hip/hip_bf16.h>

#define TTOK 4096
#define DIM  1024
#define HID  2048
#define ODIM 1024
#define NE   8

typedef __attribute__((ext_vector_type(8))) short  short8;
typedef __attribute__((ext_vector_type(4))) float  f32x4;
typedef __attribute__((ext_vector_type(8))) unsigned short ushort8;

#define WAITVM(N) asm volatile("s_waitcnt vmcnt(" #N ")" ::: "memory")
#define BAR() __builtin_amdgcn_s_barrier()

__device__ __forceinline__ unsigned short f2bf(float f){
  unsigned u = __float_as_uint(f);
  u += 0x7fffu + ((u >> 16) & 1u);
  return (unsigned short)(u >> 16);
}

__device__ __forceinline__ void gld16(const void* g, void* l){
  __builtin_amdgcn_global_load_lds(
      (const __attribute__((address_space(1))) unsigned int*)g,
      (__attribute__((address_space(3))) unsigned int*)l, 16, 0, 0);
}

// ---------------- router: logits(f32) -> top2 + weights, x -> bf16 ----------
__global__ __launch_bounds__(256) void router_kernel(
    const float* __restrict__ x, const float* __restrict__ rw,
    const float* __restrict__ rb, unsigned short* __restrict__ xbf,
    int2* __restrict__ toke, float2* __restrict__ tokw)
{
  int tok  = (blockIdx.x * blockDim.x + threadIdx.x) >> 6;
  int lane = threadIdx.x & 63;
  const float4* xr = (const float4*)(x + (size_t)tok * DIM + lane * 16);
  float xv[16];
#pragma unroll
  for (int q = 0; q < 4; q++){
    float4 v = xr[q];
    xv[q*4+0]=v.x; xv[q*4+1]=v.y; xv[q*4+2]=v.z; xv[q*4+3]=v.w;
  }
  ushort8 u0, u1;
#pragma unroll
  for (int j = 0; j < 8; j++){ u0[j] = f2bf(xv[j]); u1[j] = f2bf(xv[8+j]); }
  ushort8* xo = (ushort8*)(xbf + (size_t)tok * DIM + lane * 16);
  xo[0] = u0; xo[1] = u1;

  float lg[NE];
#pragma unroll
  for (int e = 0; e < NE; e++){
    const float4* wr4 = (const float4*)(rw + (size_t)e * DIM + lane * 16);
    float s = 0.f;
#pragma unroll
    for (int q = 0; q < 4; q++){
      float4 wv = wr4[q];
      s += xv[q*4+0]*wv.x + xv[q*4+1]*wv.y + xv[q*4+2]*wv.z + xv[q*4+3]*wv.w;
    }
    lg[e] = s;
  }
#pragma unroll
  for (int e = 0; e < NE; e++)
    for (int s = 1; s < 64; s <<= 1) lg[e] += __shfl_xor(lg[e], s, 64);

  if (lane == 0){
#pragma unroll
    for (int e = 0; e < NE; e++) lg[e] += rb[e];
    int e0 = 0; float l0 = lg[0];
    for (int e = 1; e < NE; e++) if (lg[e] > l0){ l0 = lg[e]; e0 = e; }
    int e1 = -1; float l1 = -1e30f;
    for (int e = 0; e < NE; e++) if (e != e0 && lg[e] > l1){ l1 = lg[e]; e1 = e; }
    float w0 = 1.f / (1.f + __expf(l1 - l0));
    float w1 = 1.f / (1.f + __expf(l0 - l1));
    toke[tok] = make_int2(e0, e1);
    tokw[tok] = make_float2(w0, w1);
  }
}

// ---- plan: per-expert compact lists, counts, offsets. Atomic-free. ---------
__global__ __launch_bounds__(256) void plan_kernel(
    const int2* __restrict__ toke, const float2* __restrict__ tokw,
    int* __restrict__ counts, int* __restrict__ offs,
    int* __restrict__ tlist, float* __restrict__ wlist)
{
  const int e  = blockIdx.x;
  const int t  = threadIdx.x;
  const int lane = t & 63, wv = t >> 6;
  __shared__ int sh[4 * 8];
  __shared__ int tot[8];
  __shared__ int sw[4];

  int wcnt[NE];
#pragma unroll
  for (int ee = 0; ee < NE; ee++) wcnt[ee] = 0;
  for (int base = 0; base < TTOK; base += 256){
    int2 p = toke[base + t];
#pragma unroll
    for (int ee = 0; ee < NE; ee++){
      unsigned long long m = __ballot(p.x == ee || p.y == ee);
      if (lane == 0) wcnt[ee] += __popcll(m);
    }
  }
  if (lane == 0){
#pragma unroll
    for (int ee = 0; ee < NE; ee++) sh[wv * 8 + ee] = wcnt[ee];
  }
  __syncthreads();
  if (t < NE) tot[t] = sh[t] + sh[8 + t] + sh[16 + t] + sh[24 + t];
  __syncthreads();

  int my_off = 0;
#pragma unroll
  for (int ee = 0; ee < NE; ee++) if (ee < e) my_off += tot[ee];

  if (e == 0 && t < NE){
    counts[t] = tot[t];
    int o = 0;
    for (int ee = 0; ee < NE; ee++){ if (ee < t) o += tot[ee]; }
    offs[t] = o;
    if (t == 0){
      int s = 0;
      for (int ee = 0; ee < NE; ee++) s += tot[ee];
      offs[NE] = s;
    }
  }

  int running = my_off;
  for (int base = 0; base < TTOK; base += 256){
    int tokid = base + t;
    int2  p = toke[tokid];
    float2 wgt = tokw[tokid];
    bool s0 = (p.x == e), s1 = (p.y == e);
    bool flag = s0 || s1;
    unsigned long long m = __ballot(flag);
    int rank_in_wave = __popcll(m & ((lane == 0) ? 0ull : ((~0ull) >> (64 - lane))));
    if (lane == 0) sw[wv] = __popcll(m);
    __syncthreads();
    int wave_base = 0, tot4 = 0;
#pragma unroll
    for (int w2 = 0; w2 < 4; w2++){ int v = sw[w2]; tot4 += v; if (w2 < wv) wave_base += v; }
    if (flag){
      int pos = running + wave_base + rank_in_wave;
      tlist[pos] = tokid;
      wlist[pos] = s0 ? wgt.x : wgt.y;
    }
    running += tot4;
    __syncthreads();
  }
}

// ------- transpose+convert: in [E][R][C] f32 -> out [E][C][R] bf16 ----------
__global__ __launch_bounds__(256) void transpose_cvt(
    const float* __restrict__ in, unsigned short* __restrict__ out, int R, int C)
{
  __shared__ __align__(16) unsigned short tl[64 * 128];
  int e = blockIdx.z;
  const float* src = in + (size_t)e * R * C + (size_t)(blockIdx.y * 128) * C + blockIdx.x * 64;
  unsigned short* dst = out + (size_t)e * C * R + (size_t)(blockIdx.x * 64) * R + blockIdx.y * 128;
  int t = threadIdx.x;
#pragma unroll
  for (int i = 0; i < 8; i++){
    int idx = i * 256 + t;
    int c = idx & 63, r0 = (idx >> 6) * 4;
    unsigned short v[4];
#pragma unroll
    for (int j = 0; j < 4; j++) v[j] = f2bf(src[(size_t)(r0 + j) * C + c]);
    unsigned long long pk = (unsigned long long)v[0] | ((unsigned long long)v[1] << 16)
      | ((unsigned long long)v[2] << 32) | ((unsigned long long)v[3] << 48);
    *(unsigned long long*)((char*)tl + c * 256 + (((r0 >> 3) ^ (c & 15)) * 16) + (r0 & 7) * 2) = pk;
  }
  __syncthreads();
#pragma unroll
  for (int i = 0; i < 4; i++){
    int idx = i * 256 + t;
    int c = idx >> 4, r0 = (idx & 15) * 8;
    ushort8 u = *(const ushort8*)((const char*)tl + c * 256 + (((r0 >> 3) ^ (c & 15)) * 16));
    *(ushort8*)(dst + (size_t)c * R + r0) = u;
  }
}

// ---------------- stage 1: h=X@W1, g=X@W3, a = silu(h)*g  (bf16) ------------
// 3-deep pipelined staging: raw s_barrier + counted vmcnt (never 0 in main
// loop).  Per step: vmcnt(12) -> bar -> ds_read+MFMA -> bar -> STAGE(k+3).
__global__ __launch_bounds__(256,2) void ffn1_kernel(
    const unsigned short* __restrict__ xbf,
    const unsigned short* __restrict__ w1t,
    const unsigned short* __restrict__ w3t,
    unsigned short* __restrict__ abuf,
    const int* __restrict__ counts, const int* __restrict__ offs,
    const int* __restrict__ tlist)
{
  const int e = blockIdx.x, ct = blockIdx.y, rt = blockIdx.z;
  const int cnt = counts[e];
  const int rbase = rt * 128;
  if (rbase >= cnt) return;
  const int off = offs[e];
  const int rows_left = cnt - rbase;
  const int t = threadIdx.x;
  const int lane = t & 63, w = t >> 6;
  const int wr = w >> 1, wc = w & 1;

  // [3 buffers][A:4096 | B1:4096 | B3:4096 elems] = 72 KB
  __shared__ __align__(16) unsigned short lds[3 * 12288];

  int ar0 = t >> 2, ar1 = 64 + (t >> 2);
  int psw = (t & 3) ^ ((t >> 3) & 3);        // pre-swizzled source chunk
  int ra0 = ar0 < rows_left ? ar0 : rows_left - 1;
  int ra1 = ar1 < rows_left ? ar1 : rows_left - 1;
  int tok0 = tlist[off + rbase + ra0];
  int tok1 = tlist[off + rbase + ra1];
  const char* sA0  = (const char*)xbf + ((size_t)tok0 * DIM) * 2 + psw * 16;
  const char* sA1  = (const char*)xbf + ((size_t)tok1 * DIM) * 2 + psw * 16;
  const char* sB10 = (const char*)w1t + (((size_t)e * HID + ct * 128 + ar0) * DIM) * 2 + psw * 16;
  const char* sB11 = (const char*)w1t + (((size_t)e * HID + ct * 128 + ar1) * DIM) * 2 + psw * 16;
  const char* sB30 = (const char*)w3t + (((size_t)e * HID + ct * 128 + ar0) * DIM) * 2 + psw * 16;
  const char* sB31 = (const char*)w3t + (((size_t)e * HID + ct * 128 + ar1) * DIM) * 2 + psw * 16;
  const int dofs = w * 1024;

  auto STAGE = [&](int bs, int kt){
    int kb = kt << 6;                         // 64 B per K-step of 32 bf16
    char* base = (char*)lds + bs * 24576;
    gld16(sA0  + kb, base +            dofs);
    gld16(sA1  + kb, base +  4096 +    dofs);
    gld16(sB10 + kb, base +  8192 +    dofs);
    gld16(sB11 + kb, base + 12288 +    dofs);
    gld16(sB30 + kb, base + 16384 +    dofs);
    gld16(sB31 + kb, base + 20480 +    dofs);
  };

  const int chsw = ((lane >> 4) ^ ((lane >> 1) & 3)) * 8;  // swizzled read chunk
  int aofs[4], b1ofs[4], b3ofs[4];
#pragma unroll
  for (int i = 0; i < 4; i++){
    int am = wr * 64 + i * 16 + (lane & 15);
    int bn = wc * 64 + i * 16 + (lane & 15);
    aofs[i]  = am * 32 + chsw;
    b1ofs[i] = 4096 + bn * 32 + chsw;
    b3ofs[i] = 8192 + bn * 32 + chsw;
  }

  f32x4 acch[4][4], accg[4][4];
#pragma unroll
  for (int i = 0; i < 4; i++)
#pragma unroll
    for (int j = 0; j < 4; j++){
      acch[i][j] = (f32x4){0.f,0.f,0.f,0.f};
      accg[i][j] = (f32x4){0.f,0.f,0.f,0.f};
    }

  auto COMPUTE = [&](int bs){
    const unsigned short* L = lds + bs * 12288;
    short8 a[4], b1[4], b3[4];
#pragma unroll
    for (int i = 0; i < 4; i++){
      a[i]  = *(const short8*)(L + aofs[i]);
      b1[i] = *(const short8*)(L + b1ofs[i]);
      b3[i] = *(const short8*)(L + b3ofs[i]);
    }
    __builtin_amdgcn_s_setprio(1);
#pragma unroll
    for (int mi = 0; mi < 4; mi++)
#pragma unroll
      for (int ni = 0; ni < 4; ni++){
        acch[mi][ni] = __builtin_amdgcn_mfma_f32_16x16x32_bf16(a[mi], b1[ni], acch[mi][ni], 0, 0, 0);
        accg[mi][ni] = __builtin_amdgcn_mfma_f32_16x16x32_bf16(a[mi], b3[ni], accg[mi][ni], 0, 0, 0);
      }
    __builtin_amdgcn_s_setprio(0);
  };

  STAGE(0, 0); STAGE(1, 1); STAGE(2, 2);
  int cur = 0;
  for (int kt = 0; kt < DIM / 32 - 3; ++kt){
    WAITVM(12); BAR();
    COMPUTE(cur);
    BAR();
    STAGE(cur, kt + 3);
    cur = (cur == 2) ? 0 : cur + 1;
  }
  WAITVM(12); BAR(); COMPUTE(cur); BAR(); cur = (cur == 2) ? 0 : cur + 1;
  WAITVM(6);  BAR(); COMPUTE(cur); BAR(); cur = (cur == 2) ? 0 : cur + 1;
  WAITVM(0);  BAR(); COMPUTE(cur);

#pragma unroll
  for (int mi = 0; mi < 4; mi++)
#pragma unroll
    for (int r = 0; r < 4; r++){
      int row_local = wr * 64 + mi * 16 + ((lane >> 4) << 2) + r;
      if (row_local < rows_left){
        size_t pair = (size_t)(off + rbase + row_local);
        unsigned short* arow = abuf + pair * HID + ct * 128 + wc * 64 + (lane & 15);
#pragma unroll
        for (int ni = 0; ni < 4; ni++){
          float h = acch[mi][ni][r], g = accg[mi][ni][r];
          float sv = h / (1.f + __expf(-h));
          arow[ni * 16] = f2bf(sv * g);
        }
      }
    }
}

// ---------------- stage 2: eo = A @ W2, scaled atomic into d_out ------------
__global__ __launch_bounds__(256,3) void ffn2_kernel(
    const unsigned short* __restrict__ abuf,
    const unsigned short* __restrict__ w2t,
    float* __restrict__ dout,
    const int* __restrict__ counts, const int* __restrict__ offs,
    const int* __restrict__ tlist, const float* __restrict__ wlist)
{
  const int e = blockIdx.x, ct = blockIdx.y, rt = blockIdx.z;
  const int cnt = counts[e];
  const int rbase = rt * 128;
  if (rbase >= cnt) return;
  const int off = offs[e];
  const int rows_left = cnt - rbase;
  const int t = threadIdx.x;
  const int lane = t & 63, w = t >> 6;
  const int wr = w >> 1, wc = w & 1;

  // [3 buffers][A:4096 | B:4096 elems] = 48 KB
  __shared__ __align__(16) unsigned short lds[3 * 8192];

  int ar0 = t >> 2, ar1 = 64 + (t >> 2);
  int psw = (t & 3) ^ ((t >> 3) & 3);
  int ra0 = ar0 < rows_left ? ar0 : rows_left - 1;
  int ra1 = ar1 < rows_left ? ar1 : rows_left - 1;
  const char* sA0 = (const char*)abuf + ((size_t)(off + rbase + ra0) * HID) * 2 + psw * 16;
  const char* sA1 = (const char*)abuf + ((size_t)(off + rbase + ra1) * HID) * 2 + psw * 16;
  const char* sB0 = (const char*)w2t + (((size_t)e * ODIM + ct * 128 + ar0) * HID) * 2 + psw * 16;
  const char* sB1 = (const char*)w2t + (((size_t)e * ODIM + ct * 128 + ar1) * HID) * 2 + psw * 16;
  const int dofs = w * 1024;

  auto STAGE = [&](int bs, int kt){
    int kb = kt << 6;
    char* base = (char*)lds + bs * 16384;
    gld16(sA0 + kb, base +           dofs);
    gld16(sA1 + kb, base +  4096 +   dofs);
    gld16(sB0 + kb, base +  8192 +   dofs);
    gld16(sB1 + kb, base + 12288 +   dofs);
  };

  const int chsw = ((lane >> 4) ^ ((lane >> 1) & 3)) * 8;
  int aofs[4], bofs[4];
#pragma unroll
  for (int i = 0; i < 4; i++){
    int am = wr * 64 + i * 16 + (lane & 15);
    int bn = wc * 64 + i * 16 + (lane & 15);
    aofs[i] = am * 32 + chsw;
    bofs[i] = 4096 + bn * 32 + chsw;
  }

  f32x4 acc[4][4];
#pragma unroll
  for (int i = 0; i < 4; i++)
#pragma unroll
    for (int j = 0; j < 4; j++) acc[i][j] = (f32x4){0.f,0.f,0.f,0.f};

  auto COMPUTE = [&](int bs){
    const unsigned short* L = lds + bs * 8192;
    short8 a[4], b[4];
#pragma unroll
    for (int i = 0; i < 4; i++){
      a[i] = *(const short8*)(L + aofs[i]);
      b[i] = *(const short8*)(L + bofs[i]);
    }
    __builtin_amdgcn_s_setprio(1);
#pragma unroll
    for (int mi = 0; mi < 4; mi++)
#pragma unroll
      for (int ni = 0; ni < 4; ni++)
        acc[mi][ni] = __builtin_amdgcn_mfma_f32_16x16x32_bf16(a[mi], b[ni], acc[mi][ni], 0, 0, 0);
    __builtin_amdgcn_s_setprio(0);
  };

  STAGE(0, 0); STAGE(1, 1); STAGE(2, 2);
  int cur = 0;
  for (int kt = 0; kt < HID / 32 - 3; ++kt){
    WAITVM(8); BAR();      // 4 loads/stage: 2 stages in flight = 8
    COMPUTE(cur);
    BAR();
    STAGE(cur, kt + 3);
    cur = (cur == 2) ? 0 : cur + 1;
  }
  WAITVM(8); BAR(); COMPUTE(cur); BAR(); cur = (cur == 2) ? 0 : cur + 1;
  WAITVM(4); BAR(); COMPUTE(cur); BAR(); cur = (cur == 2) ? 0 : cur + 1;
  WAITVM(0); BAR(); COMPUTE(cur);

#pragma unroll
  for (int mi = 0; mi < 4; mi++)
#pragma unroll
    for (int r = 0; r < 4; r++){
      int row_local = wr * 64 + mi * 16 + ((lane >> 4) << 2) + r;
      if (row_local < rows_left){
        int pair = off + rbase + row_local;
        int token = tlist[pair];
        float p   = wlist[pair];
        float* orow = dout + (size_t)token * ODIM + ct * 128 + wc * 64 + (lane & 15);
#pragma unroll
        for (int ni = 0; ni < 4; ni++)
          atomicAdd(orow + ni * 16, p * acc[mi][ni][r]);
      }
    }
}

extern "C" void kernel_launch(void* const* d_in, const int* in_sizes, int n_in,
                              void* d_out, int out_size, void* d_ws, size_t ws_size,
                              hipStream_t stream)
{
  const float* x  = (const float*)d_in[0];
  const float* rw = (const float*)d_in[1];
  const float* rb = (const float*)d_in[2];
  const float* W1 = (const float*)d_in[3];
  const float* W3 = (const float*)d_in[4];
  const float* W2 = (const float*)d_in[5];

  char* ws = (char*)d_ws;
  const size_t off_ctrl = 0;                                   // counts[8] @0, offs[9] @64B
  const size_t off_toke = 256;
  const size_t off_tokw = off_toke + (size_t)TTOK * 8;
  const size_t off_tl   = off_tokw + (size_t)TTOK * 8;
  const size_t off_wl   = off_tl   + (size_t)2 * TTOK * 4;
  const size_t off_xbf  = off_wl   + (size_t)2 * TTOK * 4;
  const size_t off_w1t  = off_xbf  + (size_t)TTOK * DIM * 2;
  const size_t off_w3t  = off_w1t  + (size_t)NE * HID * DIM * 2;
  const size_t off_w2t  = off_w3t  + (size_t)NE * HID * DIM * 2;
  const size_t off_ab   = off_w2t  + (size_t)NE * ODIM * HID * 2;
  const size_t need     = off_ab   + (size_t)2 * TTOK * HID * 2;
  if (ws_size < need) return;  // workspace too small: leave output poisoned (visible failure)

  int* counts = (int*)(ws + off_ctrl);
  int* offs   = (int*)(ws + off_ctrl + 64);
  int2*   toke = (int2*)  (ws + off_toke);
  float2* tokw = (float2*)(ws + off_tokw);
  int*    tl   = (int*)   (ws + off_tl);
  float*  wl   = (float*) (ws + off_wl);
  unsigned short* xbf = (unsigned short*)(ws + off_xbf);
  unsigned short* w1t = (unsigned short*)(ws + off_w1t);
  unsigned short* w3t = (unsigned short*)(ws + off_w3t);
  unsigned short* w2t = (unsigned short*)(ws + off_w2t);
  unsigned short* ab  = (unsigned short*)(ws + off_ab);

  hipMemsetAsync(d_out, 0, (size_t)out_size * sizeof(float), stream);

  router_kernel<<<TTOK / 4, 256, 0, stream>>>(x, rw, rb, xbf, toke, tokw);
  plan_kernel<<<NE, 256, 0, stream>>>(toke, tokw, counts, offs, tl, wl);

  transpose_cvt<<<dim3(HID / 64, DIM / 128, NE), 256, 0, stream>>>(W1, w1t, DIM, HID);
  transpose_cvt<<<dim3(HID / 64, DIM / 128, NE), 256, 0, stream>>>(W3, w3t, DIM, HID);
  transpose_cvt<<<dim3(ODIM / 64, HID / 128, NE), 256, 0, stream>>>(W2, w2t, HID, ODIM);

  ffn1_kernel<<<dim3(NE, HID / 128, 32), 256, 0, stream>>>(xbf, w1t, w3t, ab, counts, offs, tl);
  ffn2_kernel<<<dim3(NE, ODIM / 128, 32), 256, 0, stream>>>(ab, w2t, (float*)d_out, counts, offs, tl, wl);
}